// Round 1
// baseline (2616.414 us; speedup 1.0000x reference)
//
#include <hip/hip_runtime.h>
#include <math.h>

#define Bn 4
#define Dn 512
#define Sn 2048
#define Ln 8921

__device__ __forceinline__ float elu1(float x) {
    return x > 0.f ? x : expm1f(x);
}

// ---------------------------------------------------------------------------
// K/V GEMM: Out[b,s,o] = elu( sum_d W[o,d] * H[b,d,s] + bias[o] )
// H: [B, D, S] (contiguous in s), W: [D_out, D_in] row-major, Out: [B, S, D]
// 64x64 tile, BK=16, 256 threads, 4x4 per-thread microtile.
// ---------------------------------------------------------------------------
__global__ __launch_bounds__(256) void kv_gemm(const float* __restrict__ H,
                                               const float* __restrict__ W,
                                               const float* __restrict__ bias,
                                               float* __restrict__ Out) {
    int b  = blockIdx.z;
    int s0 = blockIdx.x * 64;
    int o0 = blockIdx.y * 64;
    __shared__ float As[16][64];  // [d][s]  (H tile, loaded direct)
    __shared__ float Bs[16][64];  // [d][o]  (W tile, transposed on store)
    int t  = threadIdx.x;
    int tx = t & 15, ty = t >> 4;
    int kh = t >> 4, ch = (t & 15) * 4;   // H tile: 16 rows x 16 float4
    int rw = t >> 2, cw = (t & 3) * 4;    // W tile: 64 rows x 4 float4
    float acc[4][4] = {};
    const float* Hb = H + (size_t)b * Dn * Sn;

    for (int d0 = 0; d0 < Dn; d0 += 16) {
        float4 hv = *(const float4*)(Hb + (size_t)(d0 + kh) * Sn + s0 + ch);
        float4 wv = *(const float4*)(W + (size_t)(o0 + rw) * Dn + d0 + cw);
        *(float4*)&As[kh][ch] = hv;
        Bs[cw + 0][rw] = wv.x;
        Bs[cw + 1][rw] = wv.y;
        Bs[cw + 2][rw] = wv.z;
        Bs[cw + 3][rw] = wv.w;
        __syncthreads();
#pragma unroll
        for (int kk = 0; kk < 16; ++kk) {
            float4 a4 = *(const float4*)&As[kk][ty * 4];
            float4 b4 = *(const float4*)&Bs[kk][tx * 4];
            float a[4] = {a4.x, a4.y, a4.z, a4.w};
            float bb[4] = {b4.x, b4.y, b4.z, b4.w};
#pragma unroll
            for (int i = 0; i < 4; ++i)
#pragma unroll
                for (int j = 0; j < 4; ++j)
                    acc[i][j] = fmaf(a[i], bb[j], acc[i][j]);
        }
        __syncthreads();
    }

#pragma unroll
    for (int i = 0; i < 4; ++i) {
        int s = s0 + ty * 4 + i;
        float4 o4;
        o4.x = elu1(acc[i][0] + bias[o0 + tx * 4 + 0]);
        o4.y = elu1(acc[i][1] + bias[o0 + tx * 4 + 1]);
        o4.z = elu1(acc[i][2] + bias[o0 + tx * 4 + 2]);
        o4.w = elu1(acc[i][3] + bias[o0 + tx * 4 + 3]);
        *(float4*)(Out + ((size_t)b * Sn + s) * Dn + o0 + tx * 4) = o4;
    }
}

// ---------------------------------------------------------------------------
// E GEMM: E[b,l,s] = sum_d Q[l,d] * K[b,s,d]   ("NT": both contiguous in d)
// Q: [L, D], K: [B, S, D], E written into A-region of d_out: [B, L, S]
// ---------------------------------------------------------------------------
__global__ __launch_bounds__(256) void e_gemm(const float* __restrict__ Q,
                                              const float* __restrict__ K,
                                              float* __restrict__ E) {
    int b  = blockIdx.z;
    int l0 = blockIdx.x * 64;
    int s0 = blockIdx.y * 64;
    __shared__ float As[16][64];  // [d][l]
    __shared__ float Bs[16][64];  // [d][s]
    int t  = threadIdx.x;
    int tx = t & 15, ty = t >> 4;
    int r = t >> 2, c4 = (t & 3) * 4;     // both tiles: 64 rows x 4 float4
    float acc[4][4] = {};
    const float* Kb = K + (size_t)b * Sn * Dn;

    for (int d0 = 0; d0 < Dn; d0 += 16) {
        float4 qa;
        if (l0 + r < Ln) qa = *(const float4*)(Q + (size_t)(l0 + r) * Dn + d0 + c4);
        else             qa = make_float4(0.f, 0.f, 0.f, 0.f);
        float4 kb = *(const float4*)(Kb + (size_t)(s0 + r) * Dn + d0 + c4);
        As[c4 + 0][r] = qa.x; As[c4 + 1][r] = qa.y;
        As[c4 + 2][r] = qa.z; As[c4 + 3][r] = qa.w;
        Bs[c4 + 0][r] = kb.x; Bs[c4 + 1][r] = kb.y;
        Bs[c4 + 2][r] = kb.z; Bs[c4 + 3][r] = kb.w;
        __syncthreads();
#pragma unroll
        for (int kk = 0; kk < 16; ++kk) {
            float4 a4 = *(const float4*)&As[kk][ty * 4];
            float4 b4 = *(const float4*)&Bs[kk][tx * 4];
            float a[4] = {a4.x, a4.y, a4.z, a4.w};
            float bb[4] = {b4.x, b4.y, b4.z, b4.w};
#pragma unroll
            for (int i = 0; i < 4; ++i)
#pragma unroll
                for (int j = 0; j < 4; ++j)
                    acc[i][j] = fmaf(a[i], bb[j], acc[i][j]);
        }
        __syncthreads();
    }

#pragma unroll
    for (int i = 0; i < 4; ++i) {
        int l = l0 + ty * 4 + i;
        if (l < Ln) {
            float4 o4 = {acc[i][0], acc[i][1], acc[i][2], acc[i][3]};
            *(float4*)(E + ((size_t)b * Ln + l) * Sn + s0 + tx * 4) = o4;
        }
    }
}

// ---------------------------------------------------------------------------
// Row softmax over S (in place). One block per (b,l) row; 256 thr x 8 elems.
// ---------------------------------------------------------------------------
__global__ __launch_bounds__(256) void softmax_rows(float* __restrict__ E) {
    size_t row = blockIdx.x;
    float* p = E + row * (size_t)Sn;
    int t = threadIdx.x;
    float v[8];
    float m = -INFINITY;
#pragma unroll
    for (int i = 0; i < 8; ++i) {
        v[i] = p[t + 256 * i];
        m = fmaxf(m, v[i]);
    }
#pragma unroll
    for (int off = 32; off >= 1; off >>= 1) m = fmaxf(m, __shfl_xor(m, off));
    __shared__ float sm[4];
    __shared__ float ss[4];
    int lane = t & 63, w = t >> 6;
    if (lane == 0) sm[w] = m;
    __syncthreads();
    m = fmaxf(fmaxf(sm[0], sm[1]), fmaxf(sm[2], sm[3]));
    float s = 0.f;
#pragma unroll
    for (int i = 0; i < 8; ++i) {
        v[i] = expf(v[i] - m);
        s += v[i];
    }
#pragma unroll
    for (int off = 32; off >= 1; off >>= 1) s += __shfl_xor(s, off);
    if (lane == 0) ss[w] = s;
    __syncthreads();
    s = ss[0] + ss[1] + ss[2] + ss[3];
    float inv = 1.f / s;
#pragma unroll
    for (int i = 0; i < 8; ++i) p[t + 256 * i] = v[i] * inv;
}

// ---------------------------------------------------------------------------
// C GEMM: C[b,l,o] = sum_s A[b,l,s] * V[b,s,o]   ("NN")
// A: [B, L, S] (the softmaxed output), V: [B, S, D], C: [B, L, D]
// ---------------------------------------------------------------------------
__global__ __launch_bounds__(256) void c_gemm(const float* __restrict__ A,
                                              const float* __restrict__ V,
                                              float* __restrict__ C) {
    int b  = blockIdx.z;
    int l0 = blockIdx.x * 64;
    int o0 = blockIdx.y * 64;
    __shared__ float As[16][64];  // [s][l] (transposed on store)
    __shared__ float Bs[16][64];  // [s][o] (direct)
    int t  = threadIdx.x;
    int tx = t & 15, ty = t >> 4;
    int ra = t >> 2, ca = (t & 3) * 4;    // A tile: 64 rows x 4 float4
    int kv = t >> 4, cv = (t & 15) * 4;   // V tile: 16 rows x 16 float4
    float acc[4][4] = {};
    const float* Ab = A + (size_t)b * Ln * Sn;
    const float* Vb = V + (size_t)b * Sn * Dn;

    for (int s0 = 0; s0 < Sn; s0 += 16) {
        float4 av;
        if (l0 + ra < Ln) av = *(const float4*)(Ab + (size_t)(l0 + ra) * Sn + s0 + ca);
        else              av = make_float4(0.f, 0.f, 0.f, 0.f);
        float4 vv = *(const float4*)(Vb + (size_t)(s0 + kv) * Dn + o0 + cv);
        As[ca + 0][ra] = av.x; As[ca + 1][ra] = av.y;
        As[ca + 2][ra] = av.z; As[ca + 3][ra] = av.w;
        *(float4*)&Bs[kv][cv] = vv;
        __syncthreads();
#pragma unroll
        for (int kk = 0; kk < 16; ++kk) {
            float4 a4 = *(const float4*)&As[kk][ty * 4];
            float4 b4 = *(const float4*)&Bs[kk][tx * 4];
            float a[4] = {a4.x, a4.y, a4.z, a4.w};
            float bb[4] = {b4.x, b4.y, b4.z, b4.w};
#pragma unroll
            for (int i = 0; i < 4; ++i)
#pragma unroll
                for (int j = 0; j < 4; ++j)
                    acc[i][j] = fmaf(a[i], bb[j], acc[i][j]);
        }
        __syncthreads();
    }

#pragma unroll
    for (int i = 0; i < 4; ++i) {
        int l = l0 + ty * 4 + i;
        if (l < Ln) {
            float4 o4 = {acc[i][0], acc[i][1], acc[i][2], acc[i][3]};
            *(float4*)(C + ((size_t)b * Ln + l) * Dn + o0 + tx * 4) = o4;
        }
    }
}

// ---------------------------------------------------------------------------
extern "C" void kernel_launch(void* const* d_in, const int* in_sizes, int n_in,
                              void* d_out, int out_size, void* d_ws, size_t ws_size,
                              hipStream_t stream) {
    const float* H  = (const float*)d_in[0];  // [B, D, S]
    const float* Wk = (const float*)d_in[1];  // [D, D]
    const float* bk = (const float*)d_in[2];  // [D]
    const float* Wv = (const float*)d_in[3];  // [D, D]
    const float* bv = (const float*)d_in[4];  // [D]
    const float* Q  = (const float*)d_in[5];  // [L, D]

    float* out = (float*)d_out;
    float* Cout = out;                          // [B, L, D]
    float* Aout = out + (size_t)Bn * Ln * Dn;   // [B, L, S]

    float* Kw = (float*)d_ws;                   // [B, S, D] f32 (16 MB)
    float* Vw = Kw + (size_t)Bn * Sn * Dn;      // [B, S, D] f32 (16 MB)

    // 1) K and V (1x1 conv + bias + ELU, transposed to [B,S,D])
    kv_gemm<<<dim3(Sn / 64, Dn / 64, Bn), 256, 0, stream>>>(H, Wk, bk, Kw);
    kv_gemm<<<dim3(Sn / 64, Dn / 64, Bn), 256, 0, stream>>>(H, Wv, bv, Vw);

    // 2) E = Q K^T  -> written straight into the A output region
    e_gemm<<<dim3((Ln + 63) / 64, Sn / 64, Bn), 256, 0, stream>>>(Q, Kw, Aout);

    // 3) softmax rows (in place in A region)
    softmax_rows<<<Bn * Ln, 256, 0, stream>>>(Aout);

    // 4) C = A V
    c_gemm<<<dim3((Ln + 63) / 64, Dn / 64, Bn), 256, 0, stream>>>(Aout, Vw, Cout);
}

// Round 2
// 935.374 us; speedup vs baseline: 2.7972x; 2.7972x over previous
//
#include <hip/hip_runtime.h>
#include <math.h>

#define Bn 4
#define Dn 512
#define Sn 2048
#define Ln 8921
#define Lpad 8960   // Ln rounded up to 128

typedef short bf16x8 __attribute__((ext_vector_type(8)));
typedef float f32x4 __attribute__((ext_vector_type(4)));

__device__ __forceinline__ float elu1(float x) {
    return x > 0.f ? x : expm1f(x);
}

// round-to-nearest-even f32 -> bf16 (values are finite, no NaN handling)
__device__ __forceinline__ unsigned short f2bf_rne(float f) {
    unsigned u = __float_as_uint(f);
    u += 0x7FFFu + ((u >> 16) & 1u);
    return (unsigned short)(u >> 16);
}

// pack two f32 -> two truncated bf16 in one v_perm
__device__ __forceinline__ unsigned pack_bf_trunc(float lo, float hi) {
    return __builtin_amdgcn_perm(__float_as_uint(hi), __float_as_uint(lo), 0x07060302u);
}

__device__ __forceinline__ void gld_lds16(const void* g, void* l) {
    __builtin_amdgcn_global_load_lds((const __attribute__((address_space(1))) int*)g,
                                     (__attribute__((address_space(3))) int*)l, 16, 0, 0);
}

// ---------------------------------------------------------------------------
// K/V GEMM: tmp[s,o] = elu( sum_d W[o,d] * H[b,d,s] + bias[o] ), output bf16.
// MODE 0: Out[b][s][o]  (K for e_mfma, k-major in d)
// MODE 1: Out[b][o][s]  (V^T for c_mfma, k-major in s)
// ---------------------------------------------------------------------------
template <int MODE>
__global__ __launch_bounds__(256) void kv_gemm(const float* __restrict__ H,
                                               const float* __restrict__ W,
                                               const float* __restrict__ bias,
                                               short* __restrict__ Out) {
    int b  = blockIdx.z;
    int s0 = blockIdx.x * 64;
    int o0 = blockIdx.y * 64;
    __shared__ float As[16][64];  // [d][s]
    __shared__ float Bs[16][64];  // [d][o]
    int t  = threadIdx.x;
    int tx = t & 15, ty = t >> 4;
    int kh = t >> 4, ch = (t & 15) * 4;
    int rw = t >> 2, cw = (t & 3) * 4;
    float acc[4][4] = {};
    const float* Hb = H + (size_t)b * Dn * Sn;

    for (int d0 = 0; d0 < Dn; d0 += 16) {
        float4 hv = *(const float4*)(Hb + (size_t)(d0 + kh) * Sn + s0 + ch);
        float4 wv = *(const float4*)(W + (size_t)(o0 + rw) * Dn + d0 + cw);
        *(float4*)&As[kh][ch] = hv;
        Bs[cw + 0][rw] = wv.x;
        Bs[cw + 1][rw] = wv.y;
        Bs[cw + 2][rw] = wv.z;
        Bs[cw + 3][rw] = wv.w;
        __syncthreads();
#pragma unroll
        for (int kk = 0; kk < 16; ++kk) {
            float4 a4 = *(const float4*)&As[kk][ty * 4];
            float4 b4 = *(const float4*)&Bs[kk][tx * 4];
            float a[4] = {a4.x, a4.y, a4.z, a4.w};
            float bb[4] = {b4.x, b4.y, b4.z, b4.w};
#pragma unroll
            for (int i = 0; i < 4; ++i)
#pragma unroll
                for (int j = 0; j < 4; ++j)
                    acc[i][j] = fmaf(a[i], bb[j], acc[i][j]);
        }
        __syncthreads();
    }

    if (MODE == 0) {
#pragma unroll
        for (int i = 0; i < 4; ++i) {
            int s = s0 + ty * 4 + i;
            float v[4];
#pragma unroll
            for (int j = 0; j < 4; ++j) v[j] = elu1(acc[i][j] + bias[o0 + tx * 4 + j]);
            unsigned lo = (unsigned)f2bf_rne(v[0]) | ((unsigned)f2bf_rne(v[1]) << 16);
            unsigned hi = (unsigned)f2bf_rne(v[2]) | ((unsigned)f2bf_rne(v[3]) << 16);
            *(uint2*)(Out + ((size_t)b * Sn + s) * Dn + o0 + tx * 4) = make_uint2(lo, hi);
        }
    } else {
#pragma unroll
        for (int j = 0; j < 4; ++j) {
            int o = o0 + tx * 4 + j;
            float bj = bias[o];
            float v[4];
#pragma unroll
            for (int i = 0; i < 4; ++i) v[i] = elu1(acc[i][j] + bj);
            unsigned lo = (unsigned)f2bf_rne(v[0]) | ((unsigned)f2bf_rne(v[1]) << 16);
            unsigned hi = (unsigned)f2bf_rne(v[2]) | ((unsigned)f2bf_rne(v[3]) << 16);
            *(uint2*)(Out + ((size_t)b * Dn + o) * Sn + s0 + ty * 4) = make_uint2(lo, hi);
        }
    }
}

// ---------------------------------------------------------------------------
// Q f32 [Ln][Dn] -> bf16 [Lpad][Dn], pad rows zeroed (ws is poisoned per call).
// ---------------------------------------------------------------------------
__global__ __launch_bounds__(256) void q_to_bf16(const float* __restrict__ Q,
                                                 short* __restrict__ Qb) {
    int id = blockIdx.x * 256 + threadIdx.x;  // 0 .. Lpad*64-1, 8 elems each
    int row = id >> 6, c = (id & 63) * 8;
    unsigned p[4] = {0, 0, 0, 0};
    if (row < Ln) {
        const float* src = Q + (size_t)row * Dn + c;
        float4 a = *(const float4*)src;
        float4 b = *(const float4*)(src + 4);
        p[0] = (unsigned)f2bf_rne(a.x) | ((unsigned)f2bf_rne(a.y) << 16);
        p[1] = (unsigned)f2bf_rne(a.z) | ((unsigned)f2bf_rne(a.w) << 16);
        p[2] = (unsigned)f2bf_rne(b.x) | ((unsigned)f2bf_rne(b.y) << 16);
        p[3] = (unsigned)f2bf_rne(b.z) | ((unsigned)f2bf_rne(b.w) << 16);
    }
    *(uint4*)(Qb + (size_t)id * 8) = *(uint4*)p;
}

// ---------------------------------------------------------------------------
// E = Q K^T (NT, both bf16 k-major). 128x128 tile, BK=32, 4 waves, MFMA
// 16x16x32 bf16, both operands staged via global_load_lds width=16.
// E f32 written to the A-output region [B][Ln][Sn].
// ---------------------------------------------------------------------------
__global__ __launch_bounds__(256) void e_mfma(const short* __restrict__ Qb,  // [Lpad][Dn]
                                              const short* __restrict__ Kb,  // [B][Sn][Dn]
                                              float* __restrict__ E) {       // [B][Ln][Sn]
    const int b  = blockIdx.z;
    const int m0 = blockIdx.x * 128;
    const int n0 = blockIdx.y * 128;
    __shared__ short lA[128 * 32];
    __shared__ short lB[128 * 32];
    const int t = threadIdx.x;
    const int lane = t & 63, w = t >> 6;
    const int wm = (w & 1) * 64, wn = (w >> 1) * 64;
    const int quad = lane >> 4, l15 = lane & 15;
    f32x4 acc[4][4] = {};
    const short* Ab = Qb + (size_t)m0 * Dn;
    const short* Bb = Kb + (size_t)b * Sn * Dn + (size_t)n0 * Dn;
    const int sr = t >> 2, ss = (t & 3) * 8;  // stage: row, k-segment

    for (int d0 = 0; d0 < Dn; d0 += 32) {
        gld_lds16(Ab + (size_t)sr * Dn + d0 + ss,        lA + t * 8);
        gld_lds16(Ab + (size_t)(sr + 64) * Dn + d0 + ss, lA + 2048 + t * 8);
        gld_lds16(Bb + (size_t)sr * Dn + d0 + ss,        lB + t * 8);
        gld_lds16(Bb + (size_t)(sr + 64) * Dn + d0 + ss, lB + 2048 + t * 8);
        __syncthreads();
        bf16x8 af[4], bfr[4];
#pragma unroll
        for (int i = 0; i < 4; ++i)
            af[i] = *(const bf16x8*)&lA[(wm + i * 16 + l15) * 32 + quad * 8];
#pragma unroll
        for (int j = 0; j < 4; ++j)
            bfr[j] = *(const bf16x8*)&lB[(wn + j * 16 + l15) * 32 + quad * 8];
#pragma unroll
        for (int i = 0; i < 4; ++i)
#pragma unroll
            for (int j = 0; j < 4; ++j)
                acc[i][j] = __builtin_amdgcn_mfma_f32_16x16x32_bf16(af[i], bfr[j], acc[i][j], 0, 0, 0);
        __syncthreads();
    }

#pragma unroll
    for (int i = 0; i < 4; ++i) {
        int mb = m0 + wm + i * 16 + quad * 4;
#pragma unroll
        for (int r = 0; r < 4; ++r) {
            int m = mb + r;
            if (m < Ln) {
                float* dst = E + (size_t)b * Ln * Sn + (size_t)m * Sn + n0 + wn;
#pragma unroll
                for (int j = 0; j < 4; ++j) dst[j * 16 + l15] = acc[i][j][r];
            }
        }
    }
}

// ---------------------------------------------------------------------------
// Row softmax over S (in place). One block per (b,l) row; 256 thr x 8 elems.
// ---------------------------------------------------------------------------
__global__ __launch_bounds__(256) void softmax_rows(float* __restrict__ E) {
    size_t row = blockIdx.x;
    float* p = E + row * (size_t)Sn;
    int t = threadIdx.x;
    float v[8];
    float m = -INFINITY;
#pragma unroll
    for (int i = 0; i < 8; ++i) {
        v[i] = p[t + 256 * i];
        m = fmaxf(m, v[i]);
    }
#pragma unroll
    for (int off = 32; off >= 1; off >>= 1) m = fmaxf(m, __shfl_xor(m, off));
    __shared__ float sm[4];
    __shared__ float ss[4];
    int lane = t & 63, w = t >> 6;
    if (lane == 0) sm[w] = m;
    __syncthreads();
    m = fmaxf(fmaxf(sm[0], sm[1]), fmaxf(sm[2], sm[3]));
    float s = 0.f;
#pragma unroll
    for (int i = 0; i < 8; ++i) {
        v[i] = expf(v[i] - m);
        s += v[i];
    }
#pragma unroll
    for (int off = 32; off >= 1; off >>= 1) s += __shfl_xor(s, off);
    if (lane == 0) ss[w] = s;
    __syncthreads();
    s = ss[0] + ss[1] + ss[2] + ss[3];
    float inv = 1.f / s;
#pragma unroll
    for (int i = 0; i < 8; ++i) p[t + 256 * i] = v[i] * inv;
}

// ---------------------------------------------------------------------------
// C = A V  (A f32 [B][Ln][Sn] staged with trunc-bf16 cvt; V^T bf16 via glds)
// C f32 [B][Ln][Dn]
// ---------------------------------------------------------------------------
__global__ __launch_bounds__(256) void c_mfma(const float* __restrict__ A,
                                              const short* __restrict__ Vt,  // [B][Dn][Sn]
                                              float* __restrict__ C) {
    const int b  = blockIdx.z;
    const int m0 = blockIdx.x * 128;
    const int n0 = blockIdx.y * 128;
    __shared__ short lA[128 * 32];
    __shared__ short lB[128 * 32];
    const int t = threadIdx.x;
    const int lane = t & 63, w = t >> 6;
    const int wm = (w & 1) * 64, wn = (w >> 1) * 64;
    const int quad = lane >> 4, l15 = lane & 15;
    f32x4 acc[4][4] = {};
    const float* Ab = A + (size_t)b * Ln * Sn;
    const short* Bb = Vt + (size_t)b * Dn * Sn + (size_t)n0 * Sn;
    const int ar = t >> 1, ah = (t & 1) * 16;  // A stage: row, 16-f32 half
    const int br = t >> 2, bs = (t & 3) * 8;   // B stage
    const int am = m0 + ar;
    const bool arow_ok = (am < Ln);
    const float* asrc0 = Ab + (size_t)am * Sn + ah;

    for (int s0 = 0; s0 < Sn; s0 += 32) {
        gld_lds16(Bb + (size_t)br * Sn + s0 + bs,        lB + t * 8);
        gld_lds16(Bb + (size_t)(br + 64) * Sn + s0 + bs, lB + 2048 + t * 8);
        unsigned p[8] = {0, 0, 0, 0, 0, 0, 0, 0};
        if (arow_ok) {
            const float* src = asrc0 + s0;
            float4 f0 = *(const float4*)(src);
            float4 f1 = *(const float4*)(src + 4);
            float4 f2 = *(const float4*)(src + 8);
            float4 f3 = *(const float4*)(src + 12);
            p[0] = pack_bf_trunc(f0.x, f0.y); p[1] = pack_bf_trunc(f0.z, f0.w);
            p[2] = pack_bf_trunc(f1.x, f1.y); p[3] = pack_bf_trunc(f1.z, f1.w);
            p[4] = pack_bf_trunc(f2.x, f2.y); p[5] = pack_bf_trunc(f2.z, f2.w);
            p[6] = pack_bf_trunc(f3.x, f3.y); p[7] = pack_bf_trunc(f3.z, f3.w);
        }
        *(uint4*)&lA[ar * 32 + ah]     = *(uint4*)&p[0];
        *(uint4*)&lA[ar * 32 + ah + 8] = *(uint4*)&p[4];
        __syncthreads();
        bf16x8 af[4], bfr[4];
#pragma unroll
        for (int i = 0; i < 4; ++i)
            af[i] = *(const bf16x8*)&lA[(wm + i * 16 + l15) * 32 + quad * 8];
#pragma unroll
        for (int j = 0; j < 4; ++j)
            bfr[j] = *(const bf16x8*)&lB[(wn + j * 16 + l15) * 32 + quad * 8];
#pragma unroll
        for (int i = 0; i < 4; ++i)
#pragma unroll
            for (int j = 0; j < 4; ++j)
                acc[i][j] = __builtin_amdgcn_mfma_f32_16x16x32_bf16(af[i], bfr[j], acc[i][j], 0, 0, 0);
        __syncthreads();
    }

#pragma unroll
    for (int i = 0; i < 4; ++i) {
        int mb = m0 + wm + i * 16 + quad * 4;
#pragma unroll
        for (int r = 0; r < 4; ++r) {
            int m = mb + r;
            if (m < Ln) {
                float* dst = C + (size_t)b * Ln * Dn + (size_t)m * Dn + n0 + wn;
#pragma unroll
                for (int j = 0; j < 4; ++j) dst[j * 16 + l15] = acc[i][j][r];
            }
        }
    }
}

// ---------------------------------------------------------------------------
extern "C" void kernel_launch(void* const* d_in, const int* in_sizes, int n_in,
                              void* d_out, int out_size, void* d_ws, size_t ws_size,
                              hipStream_t stream) {
    const float* H  = (const float*)d_in[0];  // [B, D, S]
    const float* Wk = (const float*)d_in[1];  // [D, D]
    const float* bk = (const float*)d_in[2];  // [D]
    const float* Wv = (const float*)d_in[3];  // [D, D]
    const float* bv = (const float*)d_in[4];  // [D]
    const float* Q  = (const float*)d_in[5];  // [L, D]

    float* out  = (float*)d_out;
    float* Cout = out;                          // [B, L, D]
    float* Aout = out + (size_t)Bn * Ln * Dn;   // [B, L, S]

    short* Kb = (short*)d_ws;                   // [B][Sn][Dn] bf16 (8 MB)
    short* Vt = Kb + (size_t)Bn * Sn * Dn;      // [B][Dn][Sn] bf16 (8 MB)
    short* Qb = Vt + (size_t)Bn * Dn * Sn;      // [Lpad][Dn] bf16 (9.2 MB)

    // 1) K (bf16 [B,S,D]) and V^T (bf16 [B,D,S])
    kv_gemm<0><<<dim3(Sn / 64, Dn / 64, Bn), 256, 0, stream>>>(H, Wk, bk, Kb);
    kv_gemm<1><<<dim3(Sn / 64, Dn / 64, Bn), 256, 0, stream>>>(H, Wv, bv, Vt);

    // 2) Q -> bf16 padded
    q_to_bf16<<<(Lpad * 64) / 256, 256, 0, stream>>>(Q, Qb);

    // 3) E = Q K^T  -> A output region (f32)
    e_mfma<<<dim3(Lpad / 128, Sn / 128, Bn), 256, 0, stream>>>(Qb, Kb, Aout);

    // 4) softmax rows (in place)
    softmax_rows<<<Bn * Ln, 256, 0, stream>>>(Aout);

    // 5) C = A V
    c_mfma<<<dim3(Lpad / 128, Dn / 128, Bn), 256, 0, stream>>>(Aout, Vt, Cout);
}

// Round 3
// 742.074 us; speedup vs baseline: 3.5258x; 1.2605x over previous
//
#include <hip/hip_runtime.h>
#include <math.h>

#define Bn 4
#define Dn 512
#define Sn 2048
#define Ln 8921
#define Lpad 8960   // Ln rounded up to 128

typedef short bf16x8 __attribute__((ext_vector_type(8)));
typedef float f32x4 __attribute__((ext_vector_type(4)));

__device__ __forceinline__ float elu1(float x) {
    return x > 0.f ? x : expm1f(x);
}

// f32 -> bf16 round-to-nearest-even, result in low 16 bits
__device__ __forceinline__ unsigned f2bf(float f) {
    unsigned u = __float_as_uint(f);
    u += 0x7FFFu + ((u >> 16) & 1u);
    return u >> 16;
}
__device__ __forceinline__ unsigned pack2(float a, float b) {
    return f2bf(a) | (f2bf(b) << 16);
}
// truncating pack (fallback path only, R2-proven)
__device__ __forceinline__ unsigned pack_bf_trunc(float lo, float hi) {
    return __builtin_amdgcn_perm(__float_as_uint(hi), __float_as_uint(lo), 0x07060302u);
}
__device__ __forceinline__ void gld_lds16(const void* g, void* l) {
    __builtin_amdgcn_global_load_lds((const __attribute__((address_space(1))) int*)g,
                                     (__attribute__((address_space(3))) int*)l, 16, 0, 0);
}

// ---------------------------------------------------------------------------
// H [B][D][S] f32 -> Ht [B][S][D] bf16 (LDS 64x64 tile transpose)
// ---------------------------------------------------------------------------
__global__ __launch_bounds__(256) void h_transpose(const float* __restrict__ H,
                                                   short* __restrict__ Ht) {
    int b = blockIdx.z;
    int s0 = blockIdx.x * 64, d0 = blockIdx.y * 64;
    __shared__ float tile[64][65];
    int t = threadIdx.x;
    int r = t >> 4, c4 = (t & 15) * 4;
    const float* Hb = H + (size_t)b * Dn * Sn;
#pragma unroll
    for (int i = 0; i < 4; ++i) {
        float4 v = *(const float4*)(Hb + (size_t)(d0 + i * 16 + r) * Sn + s0 + c4);
        *(float4*)&tile[i * 16 + r][c4] = v;  // tile[d][s]
    }
    __syncthreads();
#pragma unroll
    for (int i = 0; i < 4; ++i) {
        int srow = i * 16 + r;
        float v0 = tile[c4 + 0][srow], v1 = tile[c4 + 1][srow];
        float v2 = tile[c4 + 2][srow], v3 = tile[c4 + 3][srow];
        uint2 o = make_uint2(pack2(v0, v1), pack2(v2, v3));
        *(uint2*)(Ht + ((size_t)b * Sn + s0 + srow) * Dn + d0 + c4) = o;
    }
}

// ---------------------------------------------------------------------------
// plain f32 -> bf16 cvt (n8 = elems/8, exact multiple)
// ---------------------------------------------------------------------------
__global__ __launch_bounds__(256) void f32_to_bf16(const float* __restrict__ src,
                                                   short* __restrict__ dst, int n8) {
    int id = blockIdx.x * 256 + threadIdx.x;
    if (id >= n8) return;
    const float* s = src + (size_t)id * 8;
    float4 a = *(const float4*)s;
    float4 b = *(const float4*)(s + 4);
    uint4 o = {pack2(a.x, a.y), pack2(a.z, a.w), pack2(b.x, b.y), pack2(b.z, b.w)};
    *(uint4*)(dst + (size_t)id * 8) = o;
}

// Q f32 [Ln][Dn] -> bf16 [Lpad][Dn], pad rows zeroed
__global__ __launch_bounds__(256) void q_to_bf16(const float* __restrict__ Q,
                                                 short* __restrict__ Qb) {
    int id = blockIdx.x * 256 + threadIdx.x;  // Lpad*64 ids, 8 elems each
    int row = id >> 6, c = (id & 63) * 8;
    uint4 o = {0, 0, 0, 0};
    if (row < Ln) {
        const float* src = Q + (size_t)row * Dn + c;
        float4 a = *(const float4*)src;
        float4 b = *(const float4*)(src + 4);
        o.x = pack2(a.x, a.y); o.y = pack2(a.z, a.w);
        o.z = pack2(b.x, b.y); o.w = pack2(b.z, b.w);
    }
    *(uint4*)(Qb + (size_t)id * 8) = o;
}

// ---------------------------------------------------------------------------
// Generic NT bf16 MFMA GEMM: C[m,n] = sum_k A[m,k]*B[n,k]  (both k-major)
// 128x128 tile, BK=32, 4 waves, dual global_load_lds. n0 = blockIdx.x (fast,
// for A-tile L2/LLC reuse), m0 = blockIdx.y.
// OUT_BF16: 1 -> bf16 RNE out, 0 -> f32 out.
// EPI: 0 none, 1 elu(x+bias[n]), 2 elu(x+bias[m]).
// ---------------------------------------------------------------------------
template <int OUT_BF16, int EPI>
__global__ __launch_bounds__(256) void gemm_nt(const short* __restrict__ A,
                                               const short* __restrict__ B,
                                               const float* __restrict__ bias,
                                               void* __restrict__ Out,
                                               int K, int lda, int ldb, int ldo,
                                               int mmax,
                                               long bA, long bB, long bO) {
    const int b  = blockIdx.z;
    const int n0 = blockIdx.x * 128;
    const int m0 = blockIdx.y * 128;
    __shared__ short lA[128 * 32];
    __shared__ short lB[128 * 32];
    const int t = threadIdx.x;
    const int lane = t & 63, w = t >> 6;
    const int wm = (w & 1) * 64, wn = (w >> 1) * 64;
    const int quad = lane >> 4, l15 = lane & 15;
    f32x4 acc[4][4] = {};
    const short* Ab = A + (size_t)bA * b + (size_t)m0 * lda;
    const short* Bb = B + (size_t)bB * b + (size_t)n0 * ldb;
    const int sr = t >> 2, ss = (t & 3) * 8;

    for (int k0 = 0; k0 < K; k0 += 32) {
        gld_lds16(Ab + (size_t)sr * lda + k0 + ss,        lA + t * 8);
        gld_lds16(Ab + (size_t)(sr + 64) * lda + k0 + ss, lA + 2048 + t * 8);
        gld_lds16(Bb + (size_t)sr * ldb + k0 + ss,        lB + t * 8);
        gld_lds16(Bb + (size_t)(sr + 64) * ldb + k0 + ss, lB + 2048 + t * 8);
        __syncthreads();
        bf16x8 af[4], bfr[4];
#pragma unroll
        for (int i = 0; i < 4; ++i)
            af[i] = *(const bf16x8*)&lA[(wm + i * 16 + l15) * 32 + quad * 8];
#pragma unroll
        for (int j = 0; j < 4; ++j)
            bfr[j] = *(const bf16x8*)&lB[(wn + j * 16 + l15) * 32 + quad * 8];
#pragma unroll
        for (int i = 0; i < 4; ++i)
#pragma unroll
            for (int j = 0; j < 4; ++j)
                acc[i][j] = __builtin_amdgcn_mfma_f32_16x16x32_bf16(af[i], bfr[j], acc[i][j], 0, 0, 0);
        __syncthreads();
    }

#pragma unroll
    for (int i = 0; i < 4; ++i) {
        int mb = m0 + wm + i * 16 + quad * 4;
#pragma unroll
        for (int r = 0; r < 4; ++r) {
            int m = mb + r;
            if (m < mmax) {
                float bm = (EPI == 2) ? bias[m] : 0.f;
#pragma unroll
                for (int j = 0; j < 4; ++j) {
                    int col = n0 + wn + j * 16 + l15;
                    float v = acc[i][j][r];
                    if (EPI == 1) v = elu1(v + bias[col]);
                    if (EPI == 2) v = elu1(v + bm);
                    if (OUT_BF16)
                        ((short*)Out)[(size_t)bO * b + (size_t)m * ldo + col] = (short)f2bf(v);
                    else
                        ((float*)Out)[(size_t)bO * b + (size_t)m * ldo + col] = v;
                }
            }
        }
    }
}

// ---------------------------------------------------------------------------
// Softmax (primary): reads bf16 E in ws, writes f32 A (output) + bf16 A in place
// ---------------------------------------------------------------------------
__global__ __launch_bounds__(256) void softmax_bf16(short* __restrict__ EA,
                                                    float* __restrict__ Aout) {
    int row = blockIdx.x;  // 0..B*Ln-1
    int b = row / Ln, l = row - b * Ln;
    short* pe = EA + ((size_t)b * Lpad + l) * Sn;
    float* pa = Aout + (size_t)row * Sn;
    int t = threadIdx.x;
    uint4 raw = *(const uint4*)(pe + t * 8);
    unsigned pw[4] = {raw.x, raw.y, raw.z, raw.w};
    float v[8];
#pragma unroll
    for (int q = 0; q < 4; ++q) {
        v[2 * q]     = __uint_as_float(pw[q] << 16);
        v[2 * q + 1] = __uint_as_float(pw[q] & 0xFFFF0000u);
    }
    float m = v[0];
#pragma unroll
    for (int i = 1; i < 8; ++i) m = fmaxf(m, v[i]);
#pragma unroll
    for (int off = 32; off >= 1; off >>= 1) m = fmaxf(m, __shfl_xor(m, off));
    __shared__ float sm[4], ssum[4];
    int lane = t & 63, wv = t >> 6;
    if (lane == 0) sm[wv] = m;
    __syncthreads();
    m = fmaxf(fmaxf(sm[0], sm[1]), fmaxf(sm[2], sm[3]));
    float s = 0.f;
#pragma unroll
    for (int i = 0; i < 8; ++i) {
        v[i] = expf(v[i] - m);
        s += v[i];
    }
#pragma unroll
    for (int off = 32; off >= 1; off >>= 1) s += __shfl_xor(s, off);
    if (lane == 0) ssum[wv] = s;
    __syncthreads();
    s = ssum[0] + ssum[1] + ssum[2] + ssum[3];
    float inv = 1.f / s;
#pragma unroll
    for (int i = 0; i < 8; ++i) v[i] *= inv;
    float4 o0 = {v[0], v[1], v[2], v[3]};
    float4 o1 = {v[4], v[5], v[6], v[7]};
    *(float4*)(pa + t * 8)     = o0;
    *(float4*)(pa + t * 8 + 4) = o1;
    uint4 ob = {pack2(v[0], v[1]), pack2(v[2], v[3]), pack2(v[4], v[5]), pack2(v[6], v[7])};
    *(uint4*)(pe + t * 8) = ob;
}

// Softmax (fallback): f32 in place on the A output region
__global__ __launch_bounds__(256) void softmax_f32(float* __restrict__ E) {
    size_t row = blockIdx.x;
    float* p = E + row * (size_t)Sn;
    int t = threadIdx.x;
    float4 u0 = *(const float4*)(p + t * 8);
    float4 u1 = *(const float4*)(p + t * 8 + 4);
    float v[8] = {u0.x, u0.y, u0.z, u0.w, u1.x, u1.y, u1.z, u1.w};
    float m = v[0];
#pragma unroll
    for (int i = 1; i < 8; ++i) m = fmaxf(m, v[i]);
#pragma unroll
    for (int off = 32; off >= 1; off >>= 1) m = fmaxf(m, __shfl_xor(m, off));
    __shared__ float sm[4], ssum[4];
    int lane = t & 63, wv = t >> 6;
    if (lane == 0) sm[wv] = m;
    __syncthreads();
    m = fmaxf(fmaxf(sm[0], sm[1]), fmaxf(sm[2], sm[3]));
    float s = 0.f;
#pragma unroll
    for (int i = 0; i < 8; ++i) {
        v[i] = expf(v[i] - m);
        s += v[i];
    }
#pragma unroll
    for (int off = 32; off >= 1; off >>= 1) s += __shfl_xor(s, off);
    if (lane == 0) ssum[wv] = s;
    __syncthreads();
    s = ssum[0] + ssum[1] + ssum[2] + ssum[3];
    float inv = 1.f / s;
#pragma unroll
    for (int i = 0; i < 8; ++i) v[i] *= inv;
    float4 o0 = {v[0], v[1], v[2], v[3]};
    float4 o1 = {v[4], v[5], v[6], v[7]};
    *(float4*)(p + t * 8)     = o0;
    *(float4*)(p + t * 8 + 4) = o1;
}

// ---------------------------------------------------------------------------
// Fallback C GEMM (R2 structure, f32 A staging; grid x=n for A reuse)
// ---------------------------------------------------------------------------
__global__ __launch_bounds__(256) void c_mfma_f32(const float* __restrict__ A,
                                                  const short* __restrict__ Vt,
                                                  float* __restrict__ C) {
    const int b  = blockIdx.z;
    const int n0 = blockIdx.x * 128;
    const int m0 = blockIdx.y * 128;
    __shared__ short lA[128 * 32];
    __shared__ short lB[128 * 32];
    const int t = threadIdx.x;
    const int lane = t & 63, w = t >> 6;
    const int wm = (w & 1) * 64, wn = (w >> 1) * 64;
    const int quad = lane >> 4, l15 = lane & 15;
    f32x4 acc[4][4] = {};
    const float* Ab = A + (size_t)b * Ln * Sn;
    const short* Bb = Vt + (size_t)b * Dn * Sn + (size_t)n0 * Sn;
    const int ar = t >> 1, ah = (t & 1) * 16;
    const int br = t >> 2, bs = (t & 3) * 8;
    const int am = m0 + ar;
    const bool arow_ok = (am < Ln);
    const float* asrc0 = Ab + (size_t)am * Sn + ah;

    for (int s0 = 0; s0 < Sn; s0 += 32) {
        gld_lds16(Bb + (size_t)br * Sn + s0 + bs,        lB + t * 8);
        gld_lds16(Bb + (size_t)(br + 64) * Sn + s0 + bs, lB + 2048 + t * 8);
        unsigned p[8] = {0, 0, 0, 0, 0, 0, 0, 0};
        if (arow_ok) {
            const float* src = asrc0 + s0;
            float4 f0 = *(const float4*)(src);
            float4 f1 = *(const float4*)(src + 4);
            float4 f2 = *(const float4*)(src + 8);
            float4 f3 = *(const float4*)(src + 12);
            p[0] = pack_bf_trunc(f0.x, f0.y); p[1] = pack_bf_trunc(f0.z, f0.w);
            p[2] = pack_bf_trunc(f1.x, f1.y); p[3] = pack_bf_trunc(f1.z, f1.w);
            p[4] = pack_bf_trunc(f2.x, f2.y); p[5] = pack_bf_trunc(f2.z, f2.w);
            p[6] = pack_bf_trunc(f3.x, f3.y); p[7] = pack_bf_trunc(f3.z, f3.w);
        }
        *(uint4*)&lA[ar * 32 + ah]     = *(uint4*)&p[0];
        *(uint4*)&lA[ar * 32 + ah + 8] = *(uint4*)&p[4];
        __syncthreads();
        bf16x8 af[4], bfr[4];
#pragma unroll
        for (int i = 0; i < 4; ++i)
            af[i] = *(const bf16x8*)&lA[(wm + i * 16 + l15) * 32 + quad * 8];
#pragma unroll
        for (int j = 0; j < 4; ++j)
            bfr[j] = *(const bf16x8*)&lB[(wn + j * 16 + l15) * 32 + quad * 8];
#pragma unroll
        for (int i = 0; i < 4; ++i)
#pragma unroll
            for (int j = 0; j < 4; ++j)
                acc[i][j] = __builtin_amdgcn_mfma_f32_16x16x32_bf16(af[i], bfr[j], acc[i][j], 0, 0, 0);
        __syncthreads();
    }

#pragma unroll
    for (int i = 0; i < 4; ++i) {
        int mb = m0 + wm + i * 16 + quad * 4;
#pragma unroll
        for (int r = 0; r < 4; ++r) {
            int m = mb + r;
            if (m < Ln) {
                float* dst = C + (size_t)b * Ln * Dn + (size_t)m * Dn + n0 + wn;
#pragma unroll
                for (int j = 0; j < 4; ++j) dst[j * 16 + l15] = acc[i][j][r];
            }
        }
    }
}

// ---------------------------------------------------------------------------
extern "C" void kernel_launch(void* const* d_in, const int* in_sizes, int n_in,
                              void* d_out, int out_size, void* d_ws, size_t ws_size,
                              hipStream_t stream) {
    const float* H  = (const float*)d_in[0];  // [B, D, S]
    const float* Wk = (const float*)d_in[1];  // [D, D]
    const float* bk = (const float*)d_in[2];  // [D]
    const float* Wv = (const float*)d_in[3];  // [D, D]
    const float* bv = (const float*)d_in[4];  // [D]
    const float* Q  = (const float*)d_in[5];  // [L, D]

    float* out  = (float*)d_out;
    float* Cout = out;                          // [B, L, D]
    float* Aout = out + (size_t)Bn * Ln * Dn;   // [B, L, S]

    // ws layout (shorts):
    short* Vt  = (short*)d_ws;                        // [B][Dn][Sn]
    short* Kb  = Vt + (size_t)Bn * Dn * Sn;           // [B][Sn][Dn]
    short* Qb  = Kb + (size_t)Bn * Sn * Dn;           // [Lpad][Dn]
    short* EAb = Qb + (size_t)Lpad * Dn;              // [B][Lpad][Sn]  (primary)
    short* Ht  = EAb;                                 // [B][Sn][Dn], dead before EAb written
    short* Wkb = Ht + (size_t)Bn * Sn * Dn;           // [Dn][Dn], dead before EAb
    short* Wvb = Wkb + (size_t)Dn * Dn;               // [Dn][Dn]

    size_t need_primary =
        2 * ((size_t)Bn * Dn * Sn + (size_t)Bn * Sn * Dn + (size_t)Lpad * Dn +
             (size_t)Bn * Lpad * Sn);
    bool big = ws_size >= need_primary;

    // 1) precision prep
    h_transpose<<<dim3(Sn / 64, Dn / 64, Bn), 256, 0, stream>>>(H, Ht);
    f32_to_bf16<<<(Dn * Dn / 8 + 255) / 256, 256, 0, stream>>>(Wk, Wkb, Dn * Dn / 8);
    f32_to_bf16<<<(Dn * Dn / 8 + 255) / 256, 256, 0, stream>>>(Wv, Wvb, Dn * Dn / 8);
    q_to_bf16<<<(Lpad * 64) / 256, 256, 0, stream>>>(Q, Qb);

    // 2) K[b][s][o] = elu(Ht·Wk^T + bk)   (M=Sn, N=Dn, K=Dn)
    gemm_nt<1, 1><<<dim3(Dn / 128, Sn / 128, Bn), 256, 0, stream>>>(
        Ht, Wkb, bk, Kb, Dn, Dn, Dn, Dn, Sn,
        (long)Sn * Dn, 0L, (long)Sn * Dn);

    // 3) Vt[b][o][s] = elu(Wv·Ht^T + bv)  (M=Dn, N=Sn, K=Dn)
    gemm_nt<1, 2><<<dim3(Sn / 128, Dn / 128, Bn), 256, 0, stream>>>(
        Wvb, Ht, bv, Vt, Dn, Dn, Dn, Sn, Dn,
        0L, (long)Sn * Dn, (long)Dn * Sn);

    if (big) {
        // 4) E bf16 -> EAb   (M=Lpad, N=Sn, K=Dn)
        gemm_nt<1, 0><<<dim3(Sn / 128, Lpad / 128, Bn), 256, 0, stream>>>(
            Qb, Kb, nullptr, EAb, Dn, Dn, Dn, Sn, Ln,
            0L, (long)Sn * Dn, (long)Lpad * Sn);
        // 5) softmax: bf16 E -> f32 A out + bf16 A in place
        softmax_bf16<<<Bn * Ln, 256, 0, stream>>>(EAb, Aout);
        // 6) C = A·V   (M=Lpad, N=Dn, K=Sn)
        gemm_nt<0, 0><<<dim3(Dn / 128, Lpad / 128, Bn), 256, 0, stream>>>(
            EAb, Vt, nullptr, Cout, Sn, Sn, Sn, Dn, Ln,
            (long)Lpad * Sn, (long)Dn * Sn, (long)Ln * Dn);
    } else {
        // fallback: f32 E in A-output region
        gemm_nt<0, 0><<<dim3(Sn / 128, Lpad / 128, Bn), 256, 0, stream>>>(
            Qb, Kb, nullptr, Aout, Dn, Dn, Dn, Sn, Ln,
            0L, (long)Sn * Dn, (long)Ln * Sn);
        softmax_f32<<<Bn * Ln, 256, 0, stream>>>(Aout);
        c_mfma_f32<<<dim3(Dn / 128, Lpad / 128, Bn), 256, 0, stream>>>(Aout, Vt, Cout);
    }
}